// Round 1
// baseline (701.246 us; speedup 1.0000x reference)
//
#include <hip/hip_runtime.h>

// SimCLR fused pipeline, fp32-correct first pass.
// Stages: GEMM1 -> BN stats (2-stage, deterministic) -> GEMM2+BN+ReLU+L2norm
//         -> sim rowsum-exp (flash-style, never materializes 8192x8192)
//         -> per-row lse - pos -> mean loss.
// ws usage: ~21.7 MB fp32.

#define NB   4096
#define DIN  192
#define DHID 512
#define DOUT 128
#define N2   8192   // 2*NB

// ---------------- GEMM1: Y[v] = h_v @ W1^T + b1  (4096x512 per view) -------
__global__ __launch_bounds__(256) void gemm1_kernel(
    const float* __restrict__ h1, const float* __restrict__ h2,
    const float* __restrict__ W1, const float* __restrict__ b1,
    float* __restrict__ Y)
{
    const int v = blockIdx.z;
    const float* __restrict__ h = v ? h2 : h1;
    float* __restrict__ Yv = Y + (size_t)v * NB * DHID;
    const int r0 = blockIdx.y * 64;
    const int c0 = blockIdx.x * 64;
    __shared__ __align__(16) float As[32][68];   // [k][row], pad->16B-aligned rows
    __shared__ __align__(16) float Bs[32][68];   // [k][col]
    const int t = threadIdx.x;
    const int tm = t >> 4, tn = t & 15;
    float acc[4][4] = {};
    for (int k0 = 0; k0 < DIN; k0 += 32) {
        #pragma unroll
        for (int l = 0; l < 8; ++l) {
            int idx = l * 256 + t;
            int j = idx & 31, i = idx >> 5;
            As[j][i] = h[(size_t)(r0 + i) * DIN + k0 + j];
            Bs[j][i] = W1[(size_t)(c0 + i) * DIN + k0 + j];
        }
        __syncthreads();
        #pragma unroll
        for (int k = 0; k < 32; ++k) {
            float4 av = *(const float4*)&As[k][tm * 4];
            float4 bv = *(const float4*)&Bs[k][tn * 4];
            float a[4] = {av.x, av.y, av.z, av.w};
            float b[4] = {bv.x, bv.y, bv.z, bv.w};
            #pragma unroll
            for (int x = 0; x < 4; ++x)
                #pragma unroll
                for (int y = 0; y < 4; ++y)
                    acc[x][y] += a[x] * b[y];
        }
        __syncthreads();
    }
    #pragma unroll
    for (int x = 0; x < 4; ++x) {
        int r = r0 + tm * 4 + x;
        #pragma unroll
        for (int y = 0; y < 4; ++y) {
            int c = c0 + tn * 4 + y;
            Yv[(size_t)r * DHID + c] = acc[x][y] + b1[c];
        }
    }
}

// ---------------- BN stats stage 1: partial col sums over 256-row groups ---
__global__ __launch_bounds__(256) void bn_stats_partial(
    const float* __restrict__ Y, float* __restrict__ psumc, float* __restrict__ psqc)
{
    const int v = blockIdx.z;
    const float* __restrict__ Yv = Y + (size_t)v * NB * DHID;
    const int cl = threadIdx.x & 63;
    const int c = blockIdx.x * 64 + cl;
    const int rq = threadIdx.x >> 6;        // 0..3
    const int r0 = blockIdx.y * 256;
    float s = 0.f, s2 = 0.f;
    for (int i = 0; i < 64; ++i) {
        float yv = Yv[(size_t)(r0 + rq + i * 4) * DHID + c];
        s += yv; s2 += yv * yv;
    }
    __shared__ float ls[4][64], lq[4][64];
    ls[rq][cl] = s;
    lq[rq][cl] = s2;
    __syncthreads();
    if (rq == 0) {
        float ts = ls[0][cl] + ls[1][cl] + ls[2][cl] + ls[3][cl];
        float tq = lq[0][cl] + lq[1][cl] + lq[2][cl] + lq[3][cl];
        int g = blockIdx.y;
        psumc[((size_t)v * 16 + g) * DHID + c] = ts;
        psqc [((size_t)v * 16 + g) * DHID + c] = tq;
    }
}

// ---------------- BN stats stage 2: mean/var -> fused scale/shift ----------
__global__ __launch_bounds__(256) void bn_stats_final(
    const float* __restrict__ psumc, const float* __restrict__ psqc,
    const float* __restrict__ gamma, const float* __restrict__ beta,
    float* __restrict__ bnscale, float* __restrict__ bnshift)
{
    int id = blockIdx.x * 256 + threadIdx.x;   // 0..1023
    int v = id >> 9, c = id & 511;
    float s = 0.f, q = 0.f;
    for (int g = 0; g < 16; ++g) {
        s += psumc[((size_t)v * 16 + g) * DHID + c];
        q += psqc [((size_t)v * 16 + g) * DHID + c];
    }
    float mean = s * (1.0f / NB);
    float var  = q * (1.0f / NB) - mean * mean;
    float rstd = rsqrtf(var + 1e-5f);
    float sc = gamma[c] * rstd;
    bnscale[(size_t)v * DHID + c] = sc;
    bnshift[(size_t)v * DHID + c] = beta[c] - mean * sc;
}

// -------- GEMM2: z = relu(bn(Y)) @ W2^T + b2, then row L2-normalize --------
__global__ __launch_bounds__(256) void gemm2_kernel(
    const float* __restrict__ Y, const float* __restrict__ bnscale,
    const float* __restrict__ bnshift, const float* __restrict__ W2,
    const float* __restrict__ b2, float* __restrict__ Z, float* __restrict__ outz)
{
    const int v = blockIdx.y;
    const float* __restrict__ Yv = Y + (size_t)v * NB * DHID;
    const float* __restrict__ scv = bnscale + (size_t)v * DHID;
    const float* __restrict__ shv = bnshift + (size_t)v * DHID;
    const int r0 = blockIdx.x * 64;
    __shared__ __align__(16) float As[32][68];    // [k][row]  (bn+relu applied)
    __shared__ __align__(16) float Bs[32][132];   // [k][out_col]
    const int t = threadIdx.x;
    const int tm = t >> 4, tn = t & 15;           // 16 row-grps x 16 col-grps
    float acc[4][8] = {};
    for (int k0 = 0; k0 < DHID; k0 += 32) {
        #pragma unroll
        for (int l = 0; l < 8; ++l) {
            int idx = l * 256 + t;
            int j = idx & 31, i = idx >> 5;       // 64 rows x 32 k
            float yv = Yv[(size_t)(r0 + i) * DHID + k0 + j];
            As[j][i] = fmaxf(yv * scv[k0 + j] + shv[k0 + j], 0.f);
        }
        #pragma unroll
        for (int l = 0; l < 16; ++l) {
            int idx = l * 256 + t;
            int j = idx & 31, n = idx >> 5;       // 128 cols x 32 k
            Bs[j][n] = W2[(size_t)n * DHID + k0 + j];
        }
        __syncthreads();
        #pragma unroll
        for (int k = 0; k < 32; ++k) {
            float4 av  = *(const float4*)&As[k][tm * 4];
            float4 bv0 = *(const float4*)&Bs[k][tn * 8];
            float4 bv1 = *(const float4*)&Bs[k][tn * 8 + 4];
            float a[4] = {av.x, av.y, av.z, av.w};
            float b[8] = {bv0.x, bv0.y, bv0.z, bv0.w, bv1.x, bv1.y, bv1.z, bv1.w};
            #pragma unroll
            for (int x = 0; x < 4; ++x)
                #pragma unroll
                for (int y = 0; y < 8; ++y)
                    acc[x][y] += a[x] * b[y];
        }
        __syncthreads();
    }
    // epilogue: +b2, row L2-norm (row spread over 16 tn lanes within a wave)
    #pragma unroll
    for (int x = 0; x < 4; ++x) {
        float sq = 0.f;
        #pragma unroll
        for (int y = 0; y < 8; ++y) {
            acc[x][y] += b2[tn * 8 + y];
            sq += acc[x][y] * acc[x][y];
        }
        sq += __shfl_xor(sq, 1);
        sq += __shfl_xor(sq, 2);
        sq += __shfl_xor(sq, 4);
        sq += __shfl_xor(sq, 8);
        float inv = 1.0f / fmaxf(sqrtf(sq), 1e-12f);
        int r = r0 + tm * 4 + x;
        size_t base = ((size_t)v * NB + r) * DOUT + tn * 8;
        #pragma unroll
        for (int y = 0; y < 8; ++y) {
            float zv = acc[x][y] * inv;
            Z[base + y] = zv;      // aligned copy for sim kernel
            outz[base + y] = zv;   // d_out+1 (4B-aligned) - scalar stores
        }
    }
}

// ---- sim: per 128-row tile, partial sum over a 512-col slice of exp(2*z.z^T)
// 128x128 block tile, 8x8 thread tile, K=128 in chunks of 32. Diag masked.
__global__ __launch_bounds__(256, 4) void sim_kernel(
    const float* __restrict__ Z, float* __restrict__ psum)
{
    const int r0 = blockIdx.x * 128;
    const int cs = blockIdx.y;                 // 0..15 col-splits
    __shared__ __align__(16) float As[32][132];  // [k][row]
    __shared__ __align__(16) float Bs[32][132];  // [k][col]
    const int t = threadIdx.x;
    const int tm = t >> 4, tn = t & 15;
    float rs[8] = {};
    for (int ct = 0; ct < 4; ++ct) {
        const int c0 = (cs * 4 + ct) * 128;
        float acc[8][8] = {};
        for (int kc = 0; kc < DOUT; kc += 32) {
            #pragma unroll
            for (int l = 0; l < 16; ++l) {
                int idx = l * 256 + t;
                int j = idx & 31, i = idx >> 5;   // 128 rows x 32 k
                As[j][i] = Z[(size_t)(r0 + i) * DOUT + kc + j];
                Bs[j][i] = Z[(size_t)(c0 + i) * DOUT + kc + j];
            }
            __syncthreads();
            #pragma unroll
            for (int k = 0; k < 32; ++k) {
                float4 a0 = *(const float4*)&As[k][tm * 8];
                float4 a1 = *(const float4*)&As[k][tm * 8 + 4];
                float4 b0 = *(const float4*)&Bs[k][tn * 8];
                float4 b1 = *(const float4*)&Bs[k][tn * 8 + 4];
                float a[8] = {a0.x,a0.y,a0.z,a0.w,a1.x,a1.y,a1.z,a1.w};
                float b[8] = {b0.x,b0.y,b0.z,b0.w,b1.x,b1.y,b1.z,b1.w};
                #pragma unroll
                for (int x = 0; x < 8; ++x)
                    #pragma unroll
                    for (int y = 0; y < 8; ++y)
                        acc[x][y] += a[x] * b[y];
            }
            __syncthreads();
        }
        #pragma unroll
        for (int x = 0; x < 8; ++x) {
            int gi = r0 + tm * 8 + x;
            #pragma unroll
            for (int y = 0; y < 8; ++y) {
                int gj = c0 + tn * 8 + y;
                float e = __expf(acc[x][y] * 2.0f);   // sim in [-2,2], no overflow
                rs[x] += (gi == gj) ? 0.f : e;        // diag -> -inf excluded
            }
        }
    }
    #pragma unroll
    for (int x = 0; x < 8; ++x) {
        float s = rs[x];
        s += __shfl_xor(s, 1);
        s += __shfl_xor(s, 2);
        s += __shfl_xor(s, 4);
        s += __shfl_xor(s, 8);
        rs[x] = s;
    }
    if (tn == 0) {
        #pragma unroll
        for (int x = 0; x < 8; ++x)
            psum[(size_t)cs * N2 + r0 + tm * 8 + x] = rs[x];
    }
}

// ---------------- per-row: lse - pos ---------------------------------------
__global__ __launch_bounds__(256) void row_finalize(
    const float* __restrict__ Z, const float* __restrict__ psum,
    float* __restrict__ rowval)
{
    int i = blockIdx.x * 256 + threadIdx.x;    // 0..8191
    float s = 0.f;
    for (int cs = 0; cs < 16; ++cs) s += psum[(size_t)cs * N2 + i];
    int k = i & (NB - 1);
    const float4* z1 = (const float4*)(Z + (size_t)k * DOUT);
    const float4* z2 = (const float4*)(Z + (size_t)(k + NB) * DOUT);
    float d = 0.f;
    #pragma unroll
    for (int q = 0; q < 32; ++q) {
        float4 a = z1[q], b = z2[q];
        d += a.x*b.x + a.y*b.y + a.z*b.z + a.w*b.w;
    }
    rowval[i] = logf(s) - d * 2.0f;
}

// ---------------- loss = mean(rowval) --------------------------------------
__global__ __launch_bounds__(256) void loss_reduce(
    const float* __restrict__ rowval, float* __restrict__ out)
{
    float s = 0.f;
    for (int i = threadIdx.x; i < N2; i += 256) s += rowval[i];
    s += __shfl_xor(s, 1);
    s += __shfl_xor(s, 2);
    s += __shfl_xor(s, 4);
    s += __shfl_xor(s, 8);
    s += __shfl_xor(s, 16);
    s += __shfl_xor(s, 32);
    __shared__ float wsr[4];
    int lane = threadIdx.x & 63, w = threadIdx.x >> 6;
    if (lane == 0) wsr[w] = s;
    __syncthreads();
    if (threadIdx.x == 0)
        out[0] = (wsr[0] + wsr[1] + wsr[2] + wsr[3]) * (1.0f / N2);
}

extern "C" void kernel_launch(void* const* d_in, const int* in_sizes, int n_in,
                              void* d_out, int out_size, void* d_ws, size_t ws_size,
                              hipStream_t stream)
{
    const float* h1    = (const float*)d_in[0];
    const float* h2    = (const float*)d_in[1];
    const float* W1    = (const float*)d_in[2];
    const float* b1    = (const float*)d_in[3];
    const float* gamma = (const float*)d_in[4];
    const float* beta  = (const float*)d_in[5];
    const float* W2    = (const float*)d_in[6];
    const float* b2    = (const float*)d_in[7];
    float* out = (float*)d_out;

    float* ws      = (float*)d_ws;
    float* Y       = ws;                          // 2*4096*512 = 4,194,304
    float* psumc   = Y + (size_t)2 * NB * DHID;   // 2*16*512   = 16,384
    float* psqc    = psumc + 2 * 16 * DHID;       // 16,384
    float* bnscale = psqc + 2 * 16 * DHID;        // 1,024
    float* bnshift = bnscale + 2 * DHID;          // 1,024
    float* Z       = bnshift + 2 * DHID;          // 8192*128 = 1,048,576 (16B-aligned offset)
    float* psum    = Z + (size_t)N2 * DOUT;       // 16*8192 = 131,072
    float* rowval  = psum + (size_t)16 * N2;      // 8,192   (total ~21.7 MB)

    gemm1_kernel    <<<dim3(8, 64, 2), 256, 0, stream>>>(h1, h2, W1, b1, Y);
    bn_stats_partial<<<dim3(8, 16, 2), 256, 0, stream>>>(Y, psumc, psqc);
    bn_stats_final  <<<dim3(4),        256, 0, stream>>>(psumc, psqc, gamma, beta, bnscale, bnshift);
    gemm2_kernel    <<<dim3(64, 2),    256, 0, stream>>>(Y, bnscale, bnshift, W2, b2, Z, out + 1);
    sim_kernel      <<<dim3(64, 16),   256, 0, stream>>>(Z, psum);
    row_finalize    <<<dim3(32),       256, 0, stream>>>(Z, psum, rowval);
    loss_reduce     <<<dim3(1),        256, 0, stream>>>(rowval, out);
}

// Round 2
// 272.796 us; speedup vs baseline: 2.5706x; 2.5706x over previous
//
#include <hip/hip_runtime.h>

// SimCLR fused pipeline, round 2: sim GEMM on MFMA bf16.
// Stages: GEMM1 -> BN stats (2-stage) -> GEMM2+BN+ReLU+L2norm (writes fp32 z to
//         d_out and bf16 Zb to ws) -> sim rowsum-exp via mfma_f32_16x16x32_bf16
//         (fragments loaded DIRECTLY from global; Zb is 2MB, L2-resident)
//         -> per-row lse - pos -> mean loss.

#define NB   4096
#define DIN  192
#define DHID 512
#define DOUT 128
#define N2   8192   // 2*NB
#define NSPLIT 8    // sim col-splits

typedef short short8 __attribute__((ext_vector_type(8)));   // 8 bf16 (4 VGPRs)
typedef float floatx4 __attribute__((ext_vector_type(4)));  // MFMA C/D frag

// ---------------- GEMM1: Y[v] = h_v @ W1^T + b1  (4096x512 per view) -------
__global__ __launch_bounds__(256) void gemm1_kernel(
    const float* __restrict__ h1, const float* __restrict__ h2,
    const float* __restrict__ W1, const float* __restrict__ b1,
    float* __restrict__ Y)
{
    const int v = blockIdx.z;
    const float* __restrict__ h = v ? h2 : h1;
    float* __restrict__ Yv = Y + (size_t)v * NB * DHID;
    const int r0 = blockIdx.y * 64;
    const int c0 = blockIdx.x * 64;
    __shared__ __align__(16) float As[32][68];
    __shared__ __align__(16) float Bs[32][68];
    const int t = threadIdx.x;
    const int tm = t >> 4, tn = t & 15;
    float acc[4][4] = {};
    for (int k0 = 0; k0 < DIN; k0 += 32) {
        #pragma unroll
        for (int l = 0; l < 8; ++l) {
            int idx = l * 256 + t;
            int j = idx & 31, i = idx >> 5;
            As[j][i] = h[(size_t)(r0 + i) * DIN + k0 + j];
            Bs[j][i] = W1[(size_t)(c0 + i) * DIN + k0 + j];
        }
        __syncthreads();
        #pragma unroll
        for (int k = 0; k < 32; ++k) {
            float4 av = *(const float4*)&As[k][tm * 4];
            float4 bv = *(const float4*)&Bs[k][tn * 4];
            float a[4] = {av.x, av.y, av.z, av.w};
            float b[4] = {bv.x, bv.y, bv.z, bv.w};
            #pragma unroll
            for (int x = 0; x < 4; ++x)
                #pragma unroll
                for (int y = 0; y < 4; ++y)
                    acc[x][y] += a[x] * b[y];
        }
        __syncthreads();
    }
    #pragma unroll
    for (int x = 0; x < 4; ++x) {
        int r = r0 + tm * 4 + x;
        #pragma unroll
        for (int y = 0; y < 4; ++y) {
            int c = c0 + tn * 4 + y;
            Yv[(size_t)r * DHID + c] = acc[x][y] + b1[c];
        }
    }
}

// ---------------- BN stats stage 1: partial col sums over 256-row groups ---
__global__ __launch_bounds__(256) void bn_stats_partial(
    const float* __restrict__ Y, float* __restrict__ psumc, float* __restrict__ psqc)
{
    const int v = blockIdx.z;
    const float* __restrict__ Yv = Y + (size_t)v * NB * DHID;
    const int cl = threadIdx.x & 63;
    const int c = blockIdx.x * 64 + cl;
    const int rq = threadIdx.x >> 6;
    const int r0 = blockIdx.y * 256;
    float s = 0.f, s2 = 0.f;
    for (int i = 0; i < 64; ++i) {
        float yv = Yv[(size_t)(r0 + rq + i * 4) * DHID + c];
        s += yv; s2 += yv * yv;
    }
    __shared__ float ls[4][64], lq[4][64];
    ls[rq][cl] = s;
    lq[rq][cl] = s2;
    __syncthreads();
    if (rq == 0) {
        float ts = ls[0][cl] + ls[1][cl] + ls[2][cl] + ls[3][cl];
        float tq = lq[0][cl] + lq[1][cl] + lq[2][cl] + lq[3][cl];
        int g = blockIdx.y;
        psumc[((size_t)v * 16 + g) * DHID + c] = ts;
        psqc [((size_t)v * 16 + g) * DHID + c] = tq;
    }
}

// ---------------- BN stats stage 2: mean/var -> fused scale/shift ----------
__global__ __launch_bounds__(256) void bn_stats_final(
    const float* __restrict__ psumc, const float* __restrict__ psqc,
    const float* __restrict__ gamma, const float* __restrict__ beta,
    float* __restrict__ bnscale, float* __restrict__ bnshift)
{
    int id = blockIdx.x * 256 + threadIdx.x;
    int v = id >> 9, c = id & 511;
    float s = 0.f, q = 0.f;
    for (int g = 0; g < 16; ++g) {
        s += psumc[((size_t)v * 16 + g) * DHID + c];
        q += psqc [((size_t)v * 16 + g) * DHID + c];
    }
    float mean = s * (1.0f / NB);
    float var  = q * (1.0f / NB) - mean * mean;
    float rstd = rsqrtf(var + 1e-5f);
    float sc = gamma[c] * rstd;
    bnscale[(size_t)v * DHID + c] = sc;
    bnshift[(size_t)v * DHID + c] = beta[c] - mean * sc;
}

// -------- GEMM2: z = relu(bn(Y)) @ W2^T + b2, row L2-normalize -------------
// Writes fp32 z to outz (d_out) and bf16 z to Zb (for the MFMA sim kernel).
__global__ __launch_bounds__(256) void gemm2_kernel(
    const float* __restrict__ Y, const float* __restrict__ bnscale,
    const float* __restrict__ bnshift, const float* __restrict__ W2,
    const float* __restrict__ b2, unsigned short* __restrict__ Zb,
    float* __restrict__ outz)
{
    const int v = blockIdx.y;
    const float* __restrict__ Yv = Y + (size_t)v * NB * DHID;
    const float* __restrict__ scv = bnscale + (size_t)v * DHID;
    const float* __restrict__ shv = bnshift + (size_t)v * DHID;
    const int r0 = blockIdx.x * 64;
    __shared__ __align__(16) float As[32][68];
    __shared__ __align__(16) float Bs[32][132];
    const int t = threadIdx.x;
    const int tm = t >> 4, tn = t & 15;
    float acc[4][8] = {};
    for (int k0 = 0; k0 < DHID; k0 += 32) {
        #pragma unroll
        for (int l = 0; l < 8; ++l) {
            int idx = l * 256 + t;
            int j = idx & 31, i = idx >> 5;
            float yv = Yv[(size_t)(r0 + i) * DHID + k0 + j];
            As[j][i] = fmaxf(yv * scv[k0 + j] + shv[k0 + j], 0.f);
        }
        #pragma unroll
        for (int l = 0; l < 16; ++l) {
            int idx = l * 256 + t;
            int j = idx & 31, n = idx >> 5;
            Bs[j][n] = W2[(size_t)n * DHID + k0 + j];
        }
        __syncthreads();
        #pragma unroll
        for (int k = 0; k < 32; ++k) {
            float4 av  = *(const float4*)&As[k][tm * 4];
            float4 bv0 = *(const float4*)&Bs[k][tn * 8];
            float4 bv1 = *(const float4*)&Bs[k][tn * 8 + 4];
            float a[4] = {av.x, av.y, av.z, av.w};
            float b[8] = {bv0.x, bv0.y, bv0.z, bv0.w, bv1.x, bv1.y, bv1.z, bv1.w};
            #pragma unroll
            for (int x = 0; x < 4; ++x)
                #pragma unroll
                for (int y = 0; y < 8; ++y)
                    acc[x][y] += a[x] * b[y];
        }
        __syncthreads();
    }
    #pragma unroll
    for (int x = 0; x < 4; ++x) {
        float sq = 0.f;
        #pragma unroll
        for (int y = 0; y < 8; ++y) {
            acc[x][y] += b2[tn * 8 + y];
            sq += acc[x][y] * acc[x][y];
        }
        sq += __shfl_xor(sq, 1);
        sq += __shfl_xor(sq, 2);
        sq += __shfl_xor(sq, 4);
        sq += __shfl_xor(sq, 8);
        float inv = 1.0f / fmaxf(sqrtf(sq), 1e-12f);
        int r = r0 + tm * 4 + x;
        size_t base = ((size_t)v * NB + r) * DOUT + tn * 8;
        unsigned short hb[8];
        #pragma unroll
        for (int y = 0; y < 8; ++y) {
            float zv = acc[x][y] * inv;
            outz[base + y] = zv;
            unsigned int u = __float_as_uint(zv);
            hb[y] = (unsigned short)((u + 0x7fffu + ((u >> 16) & 1u)) >> 16); // RNE
        }
        // 16B-aligned vector store of the bf16 row chunk
        short8 pk;
        #pragma unroll
        for (int y = 0; y < 8; ++y) pk[y] = (short)hb[y];
        *(short8*)(Zb + base) = pk;
    }
}

// ---- sim: rowsum of exp(2 * Zb Zb^T) via MFMA bf16, diag masked. ----------
// No LDS: A and B fragments of mfma_f32_16x16x32_bf16 both load as
// 8 contiguous bf16 at Zb[base + (lane&15)][ (lane>>4)*8 + 32*kc ].
// Each wave owns 16 rows; block = 4 waves = 64 rows; sweeps 1024 cols.
__global__ __launch_bounds__(256) void sim_mfma(
    const unsigned short* __restrict__ Zb, float* __restrict__ psum)
{
    const int t = threadIdx.x;
    const int wave = t >> 6, lane = t & 63;
    const int quad = lane >> 4, l15 = lane & 15;
    const int mbase = blockIdx.x * 64 + wave * 16;
    const int cs = blockIdx.y;                  // 0..NSPLIT-1
    const int gi0 = mbase + quad * 4;

    // A fragments: 4 k-chunks of 32, held for the whole sweep
    const short8* zra = (const short8*)(Zb + (size_t)(mbase + l15) * DOUT + quad * 8);
    short8 a[4];
    #pragma unroll
    for (int kc = 0; kc < 4; ++kc) a[kc] = zra[kc * 4];  // +32 bf16 = 4 short8

    float rs[4] = {0.f, 0.f, 0.f, 0.f};
    const int cbase = cs * (N2 / NSPLIT);

    for (int nt = 0; nt < (N2 / NSPLIT) / 32; ++nt) {
        const int c0 = cbase + nt * 32;
        const short8* zb0 = (const short8*)(Zb + (size_t)(c0 + l15) * DOUT + quad * 8);
        const short8* zb1 = (const short8*)(Zb + (size_t)(c0 + 16 + l15) * DOUT + quad * 8);
        short8 b0[4], b1[4];
        #pragma unroll
        for (int kc = 0; kc < 4; ++kc) { b0[kc] = zb0[kc * 4]; b1[kc] = zb1[kc * 4]; }
        floatx4 acc0 = {0.f, 0.f, 0.f, 0.f};
        floatx4 acc1 = {0.f, 0.f, 0.f, 0.f};
        #pragma unroll
        for (int kc = 0; kc < 4; ++kc) {
            acc0 = __builtin_amdgcn_mfma_f32_16x16x32_bf16(a[kc], b0[kc], acc0, 0, 0, 0);
            acc1 = __builtin_amdgcn_mfma_f32_16x16x32_bf16(a[kc], b1[kc], acc1, 0, 0, 0);
        }
        const int gj0 = c0 + l15, gj1 = c0 + 16 + l15;
        #pragma unroll
        for (int r = 0; r < 4; ++r) {
            const int gi = gi0 + r;
            float e0 = __expf(acc0[r] * 2.0f);
            float e1 = __expf(acc1[r] * 2.0f);
            rs[r] += (gi == gj0 ? 0.f : e0) + (gi == gj1 ? 0.f : e1);
        }
    }
    #pragma unroll
    for (int r = 0; r < 4; ++r) {
        float s = rs[r];
        s += __shfl_xor(s, 1);
        s += __shfl_xor(s, 2);
        s += __shfl_xor(s, 4);
        s += __shfl_xor(s, 8);
        if (l15 == 0) psum[(size_t)cs * N2 + gi0 + r] = s;
    }
}

// ---------------- per-row: lse - pos (pos from bf16 Zb, fp32 accumulate) ---
__global__ __launch_bounds__(256) void row_finalize(
    const unsigned short* __restrict__ Zb, const float* __restrict__ psum,
    float* __restrict__ rowval)
{
    int i = blockIdx.x * 256 + threadIdx.x;
    float s = 0.f;
    #pragma unroll
    for (int cs = 0; cs < NSPLIT; ++cs) s += psum[(size_t)cs * N2 + i];
    int k = i & (NB - 1);
    const uint4* z1 = (const uint4*)(Zb + (size_t)k * DOUT);
    const uint4* z2 = (const uint4*)(Zb + (size_t)(k + NB) * DOUT);
    float d = 0.f;
    #pragma unroll
    for (int q = 0; q < 16; ++q) {        // 16 x 8 bf16 = 128
        uint4 a = z1[q], b = z2[q];
        const unsigned int aw[4] = {a.x, a.y, a.z, a.w};
        const unsigned int bw[4] = {b.x, b.y, b.z, b.w};
        #pragma unroll
        for (int c = 0; c < 4; ++c) {
            float alo = __uint_as_float(aw[c] << 16);
            float ahi = __uint_as_float(aw[c] & 0xffff0000u);
            float blo = __uint_as_float(bw[c] << 16);
            float bhi = __uint_as_float(bw[c] & 0xffff0000u);
            d += alo * blo + ahi * bhi;
        }
    }
    rowval[i] = logf(s) - d * 2.0f;
}

// ---------------- loss = mean(rowval) --------------------------------------
__global__ __launch_bounds__(256) void loss_reduce(
    const float* __restrict__ rowval, float* __restrict__ out)
{
    float s = 0.f;
    for (int i = threadIdx.x; i < N2; i += 256) s += rowval[i];
    s += __shfl_xor(s, 1);
    s += __shfl_xor(s, 2);
    s += __shfl_xor(s, 4);
    s += __shfl_xor(s, 8);
    s += __shfl_xor(s, 16);
    s += __shfl_xor(s, 32);
    __shared__ float wsr[4];
    int lane = threadIdx.x & 63, w = threadIdx.x >> 6;
    if (lane == 0) wsr[w] = s;
    __syncthreads();
    if (threadIdx.x == 0)
        out[0] = (wsr[0] + wsr[1] + wsr[2] + wsr[3]) * (1.0f / N2);
}

extern "C" void kernel_launch(void* const* d_in, const int* in_sizes, int n_in,
                              void* d_out, int out_size, void* d_ws, size_t ws_size,
                              hipStream_t stream)
{
    const float* h1    = (const float*)d_in[0];
    const float* h2    = (const float*)d_in[1];
    const float* W1    = (const float*)d_in[2];
    const float* b1    = (const float*)d_in[3];
    const float* gamma = (const float*)d_in[4];
    const float* beta  = (const float*)d_in[5];
    const float* W2    = (const float*)d_in[6];
    const float* b2    = (const float*)d_in[7];
    float* out = (float*)d_out;

    float* ws      = (float*)d_ws;
    float* Y       = ws;                          // 2*4096*512 = 4,194,304 f
    float* psumc   = Y + (size_t)2 * NB * DHID;   // 16,384 f
    float* psqc    = psumc + 2 * 16 * DHID;       // 16,384 f
    float* bnscale = psqc + 2 * 16 * DHID;        // 1,024 f
    float* bnshift = bnscale + 2 * DHID;          // 1,024 f
    float* psum    = bnshift + 2 * DHID;          // NSPLIT*8192 = 65,536 f
    float* rowval  = psum + (size_t)NSPLIT * N2;  // 8,192 f
    unsigned short* Zb = (unsigned short*)(rowval + N2);  // 8192*128 bf16 = 2MB
    // total ~ 19.3 MB

    gemm1_kernel    <<<dim3(8, 64, 2), 256, 0, stream>>>(h1, h2, W1, b1, Y);
    bn_stats_partial<<<dim3(8, 16, 2), 256, 0, stream>>>(Y, psumc, psqc);
    bn_stats_final  <<<dim3(4),        256, 0, stream>>>(psumc, psqc, gamma, beta, bnscale, bnshift);
    gemm2_kernel    <<<dim3(64, 2),    256, 0, stream>>>(Y, bnscale, bnshift, W2, b2, Zb, out + 1);
    sim_mfma        <<<dim3(128, NSPLIT), 256, 0, stream>>>(Zb, psum);
    row_finalize    <<<dim3(32),       256, 0, stream>>>(Zb, psum, rowval);
    loss_reduce     <<<dim3(1),        256, 0, stream>>>(rowval, out);
}

// Round 4
// 200.556 us; speedup vs baseline: 3.4965x; 1.3602x over previous
//
#include <hip/hip_runtime.h>

// SimCLR fused pipeline, round 3 resubmit (round-3 bench died on infra error).
// sim: each wave owns 64 rows (4 MFMA A-tiles held in regs); per iter loads one
// 16-col B-tile (next-iter, double-buffered) and runs 16 MFMA + 16 exp.
// Load:MFMA = 1:4, loads in flight during compute.

#define NB   4096
#define DIN  192
#define DHID 512
#define DOUT 128
#define N2   8192   // 2*NB
#define NSPLIT 32   // sim col-splits (grid.y); 256 cols per block
#define SIM_ITERS 16  // 256 cols / 16 per tile

typedef short short8 __attribute__((ext_vector_type(8)));   // 8 bf16 (4 VGPRs)
typedef float floatx4 __attribute__((ext_vector_type(4)));  // MFMA C/D frag

// ---------------- GEMM1: Y[v] = h_v @ W1^T + b1  (4096x512 per view) -------
__global__ __launch_bounds__(256) void gemm1_kernel(
    const float* __restrict__ h1, const float* __restrict__ h2,
    const float* __restrict__ W1, const float* __restrict__ b1,
    float* __restrict__ Y)
{
    const int v = blockIdx.z;
    const float* __restrict__ h = v ? h2 : h1;
    float* __restrict__ Yv = Y + (size_t)v * NB * DHID;
    const int r0 = blockIdx.y * 64;
    const int c0 = blockIdx.x * 64;
    __shared__ __align__(16) float As[32][68];
    __shared__ __align__(16) float Bs[32][68];
    const int t = threadIdx.x;
    const int tm = t >> 4, tn = t & 15;
    float acc[4][4] = {};
    for (int k0 = 0; k0 < DIN; k0 += 32) {
        #pragma unroll
        for (int l = 0; l < 8; ++l) {
            int idx = l * 256 + t;
            int j = idx & 31, i = idx >> 5;
            As[j][i] = h[(size_t)(r0 + i) * DIN + k0 + j];
            Bs[j][i] = W1[(size_t)(c0 + i) * DIN + k0 + j];
        }
        __syncthreads();
        #pragma unroll
        for (int k = 0; k < 32; ++k) {
            float4 av = *(const float4*)&As[k][tm * 4];
            float4 bv = *(const float4*)&Bs[k][tn * 4];
            float a[4] = {av.x, av.y, av.z, av.w};
            float b[4] = {bv.x, bv.y, bv.z, bv.w};
            #pragma unroll
            for (int x = 0; x < 4; ++x)
                #pragma unroll
                for (int y = 0; y < 4; ++y)
                    acc[x][y] += a[x] * b[y];
        }
        __syncthreads();
    }
    #pragma unroll
    for (int x = 0; x < 4; ++x) {
        int r = r0 + tm * 4 + x;
        #pragma unroll
        for (int y = 0; y < 4; ++y) {
            int c = c0 + tn * 4 + y;
            Yv[(size_t)r * DHID + c] = acc[x][y] + b1[c];
        }
    }
}

// ---------------- BN stats stage 1: partial col sums over 256-row groups ---
__global__ __launch_bounds__(256) void bn_stats_partial(
    const float* __restrict__ Y, float* __restrict__ psumc, float* __restrict__ psqc)
{
    const int v = blockIdx.z;
    const float* __restrict__ Yv = Y + (size_t)v * NB * DHID;
    const int cl = threadIdx.x & 63;
    const int c = blockIdx.x * 64 + cl;
    const int rq = threadIdx.x >> 6;
    const int r0 = blockIdx.y * 256;
    float s = 0.f, s2 = 0.f;
    for (int i = 0; i < 64; ++i) {
        float yv = Yv[(size_t)(r0 + rq + i * 4) * DHID + c];
        s += yv; s2 += yv * yv;
    }
    __shared__ float ls[4][64], lq[4][64];
    ls[rq][cl] = s;
    lq[rq][cl] = s2;
    __syncthreads();
    if (rq == 0) {
        float ts = ls[0][cl] + ls[1][cl] + ls[2][cl] + ls[3][cl];
        float tq = lq[0][cl] + lq[1][cl] + lq[2][cl] + lq[3][cl];
        int g = blockIdx.y;
        psumc[((size_t)v * 16 + g) * DHID + c] = ts;
        psqc [((size_t)v * 16 + g) * DHID + c] = tq;
    }
}

// ---------------- BN stats stage 2: mean/var -> fused scale/shift ----------
__global__ __launch_bounds__(256) void bn_stats_final(
    const float* __restrict__ psumc, const float* __restrict__ psqc,
    const float* __restrict__ gamma, const float* __restrict__ beta,
    float* __restrict__ bnscale, float* __restrict__ bnshift)
{
    int id = blockIdx.x * 256 + threadIdx.x;
    int v = id >> 9, c = id & 511;
    float s = 0.f, q = 0.f;
    for (int g = 0; g < 16; ++g) {
        s += psumc[((size_t)v * 16 + g) * DHID + c];
        q += psqc [((size_t)v * 16 + g) * DHID + c];
    }
    float mean = s * (1.0f / NB);
    float var  = q * (1.0f / NB) - mean * mean;
    float rstd = rsqrtf(var + 1e-5f);
    float sc = gamma[c] * rstd;
    bnscale[(size_t)v * DHID + c] = sc;
    bnshift[(size_t)v * DHID + c] = beta[c] - mean * sc;
}

// -------- GEMM2: z = relu(bn(Y)) @ W2^T + b2, row L2-normalize -------------
__global__ __launch_bounds__(256) void gemm2_kernel(
    const float* __restrict__ Y, const float* __restrict__ bnscale,
    const float* __restrict__ bnshift, const float* __restrict__ W2,
    const float* __restrict__ b2, unsigned short* __restrict__ Zb,
    float* __restrict__ outz)
{
    const int v = blockIdx.y;
    const float* __restrict__ Yv = Y + (size_t)v * NB * DHID;
    const float* __restrict__ scv = bnscale + (size_t)v * DHID;
    const float* __restrict__ shv = bnshift + (size_t)v * DHID;
    const int r0 = blockIdx.x * 64;
    __shared__ __align__(16) float As[32][68];
    __shared__ __align__(16) float Bs[32][132];
    const int t = threadIdx.x;
    const int tm = t >> 4, tn = t & 15;
    float acc[4][8] = {};
    for (int k0 = 0; k0 < DHID; k0 += 32) {
        #pragma unroll
        for (int l = 0; l < 8; ++l) {
            int idx = l * 256 + t;
            int j = idx & 31, i = idx >> 5;
            float yv = Yv[(size_t)(r0 + i) * DHID + k0 + j];
            As[j][i] = fmaxf(yv * scv[k0 + j] + shv[k0 + j], 0.f);
        }
        #pragma unroll
        for (int l = 0; l < 16; ++l) {
            int idx = l * 256 + t;
            int j = idx & 31, n = idx >> 5;
            Bs[j][n] = W2[(size_t)n * DHID + k0 + j];
        }
        __syncthreads();
        #pragma unroll
        for (int k = 0; k < 32; ++k) {
            float4 av  = *(const float4*)&As[k][tm * 4];
            float4 bv0 = *(const float4*)&Bs[k][tn * 8];
            float4 bv1 = *(const float4*)&Bs[k][tn * 8 + 4];
            float a[4] = {av.x, av.y, av.z, av.w};
            float b[8] = {bv0.x, bv0.y, bv0.z, bv0.w, bv1.x, bv1.y, bv1.z, bv1.w};
            #pragma unroll
            for (int x = 0; x < 4; ++x)
                #pragma unroll
                for (int y = 0; y < 8; ++y)
                    acc[x][y] += a[x] * b[y];
        }
        __syncthreads();
    }
    #pragma unroll
    for (int x = 0; x < 4; ++x) {
        float sq = 0.f;
        #pragma unroll
        for (int y = 0; y < 8; ++y) {
            acc[x][y] += b2[tn * 8 + y];
            sq += acc[x][y] * acc[x][y];
        }
        sq += __shfl_xor(sq, 1);
        sq += __shfl_xor(sq, 2);
        sq += __shfl_xor(sq, 4);
        sq += __shfl_xor(sq, 8);
        float inv = 1.0f / fmaxf(sqrtf(sq), 1e-12f);
        int r = r0 + tm * 4 + x;
        size_t base = ((size_t)v * NB + r) * DOUT + tn * 8;
        unsigned short hb[8];
        #pragma unroll
        for (int y = 0; y < 8; ++y) {
            float zv = acc[x][y] * inv;
            outz[base + y] = zv;
            unsigned int u = __float_as_uint(zv);
            hb[y] = (unsigned short)((u + 0x7fffu + ((u >> 16) & 1u)) >> 16); // RNE
        }
        short8 pk;
        #pragma unroll
        for (int y = 0; y < 8; ++y) pk[y] = (short)hb[y];
        *(short8*)(Zb + base) = pk;
    }
}

// ---- sim: rowsum of exp(2 * Zb Zb^T) via MFMA bf16, diag masked. ----------
// Wave owns 64 rows = 4 A-tiles (16 regs x4 held for whole sweep).
// Per iter: double-buffered load of ONE 16-col B-tile (4 short8), 16 MFMA,
// 16 exp2. Block = 4 waves = 256 rows; sweeps 256 cols (NSPLIT=32 splits).
__global__ __launch_bounds__(256, 3) void sim_mfma(
    const unsigned short* __restrict__ Zb, float* __restrict__ psum)
{
    const int t = threadIdx.x;
    const int wave = t >> 6, lane = t & 63;
    const int quad = lane >> 4, l15 = lane & 15;
    const int mbase = blockIdx.x * 256 + wave * 64;   // 64 rows per wave
    const int cs = blockIdx.y;                        // 0..NSPLIT-1
    const int cbase = cs * (N2 / NSPLIT);             // 256-col slice

    // A fragments: 4 row-tiles x 4 k-chunks, held in regs for the whole sweep
    short8 a[4][4];
    #pragma unroll
    for (int at = 0; at < 4; ++at) {
        const short8* zra = (const short8*)(Zb + (size_t)(mbase + at * 16 + l15) * DOUT + quad * 8);
        #pragma unroll
        for (int kc = 0; kc < 4; ++kc) a[at][kc] = zra[kc * 4];  // +32 bf16 stride
    }

    float rs[4][4];
    #pragma unroll
    for (int at = 0; at < 4; ++at)
        #pragma unroll
        for (int r = 0; r < 4; ++r) rs[at][r] = 0.f;

    // prologue: load B-tile 0
    short8 bcur[4], bnext[4];
    {
        const short8* zb = (const short8*)(Zb + (size_t)(cbase + l15) * DOUT + quad * 8);
        #pragma unroll
        for (int kc = 0; kc < 4; ++kc) bcur[kc] = zb[kc * 4];
    }

    for (int nt = 0; nt < SIM_ITERS; ++nt) {
        // prefetch next B-tile (wraps to tile 0 on last iter; harmless)
        const int cn = cbase + ((nt + 1) & (SIM_ITERS - 1)) * 16;
        const short8* zbn = (const short8*)(Zb + (size_t)(cn + l15) * DOUT + quad * 8);
        #pragma unroll
        for (int kc = 0; kc < 4; ++kc) bnext[kc] = zbn[kc * 4];

        floatx4 acc[4] = {{0.f,0.f,0.f,0.f},{0.f,0.f,0.f,0.f},
                          {0.f,0.f,0.f,0.f},{0.f,0.f,0.f,0.f}};
        #pragma unroll
        for (int kc = 0; kc < 4; ++kc)
            #pragma unroll
            for (int at = 0; at < 4; ++at)
                acc[at] = __builtin_amdgcn_mfma_f32_16x16x32_bf16(a[at][kc], bcur[kc], acc[at], 0, 0, 0);

        const int gj = cbase + nt * 16 + l15;
        #pragma unroll
        for (int at = 0; at < 4; ++at) {
            const int gi0 = mbase + at * 16 + quad * 4;
            #pragma unroll
            for (int r = 0; r < 4; ++r) {
                // exp(2*x) = exp2(x * 2*log2(e))
                float e = exp2f(acc[at][r] * 2.8853900817779268f);
                rs[at][r] += (gi0 + r == gj) ? 0.f : e;
            }
        }
        #pragma unroll
        for (int kc = 0; kc < 4; ++kc) bcur[kc] = bnext[kc];
    }

    #pragma unroll
    for (int at = 0; at < 4; ++at) {
        const int gi0 = mbase + at * 16 + quad * 4;
        #pragma unroll
        for (int r = 0; r < 4; ++r) {
            float s = rs[at][r];
            s += __shfl_xor(s, 1);
            s += __shfl_xor(s, 2);
            s += __shfl_xor(s, 4);
            s += __shfl_xor(s, 8);
            if (l15 == 0) psum[(size_t)cs * N2 + gi0 + r] = s;
        }
    }
}

// ---------------- per-row: lse - pos (pos from bf16 Zb, fp32 accumulate) ---
__global__ __launch_bounds__(256) void row_finalize(
    const unsigned short* __restrict__ Zb, const float* __restrict__ psum,
    float* __restrict__ rowval)
{
    int i = blockIdx.x * 256 + threadIdx.x;
    float s = 0.f;
    #pragma unroll
    for (int cs = 0; cs < NSPLIT; ++cs) s += psum[(size_t)cs * N2 + i];
    int k = i & (NB - 1);
    const uint4* z1 = (const uint4*)(Zb + (size_t)k * DOUT);
    const uint4* z2 = (const uint4*)(Zb + (size_t)(k + NB) * DOUT);
    float d = 0.f;
    #pragma unroll
    for (int q = 0; q < 16; ++q) {
        uint4 a = z1[q], b = z2[q];
        const unsigned int aw[4] = {a.x, a.y, a.z, a.w};
        const unsigned int bw[4] = {b.x, b.y, b.z, b.w};
        #pragma unroll
        for (int c = 0; c < 4; ++c) {
            float alo = __uint_as_float(aw[c] << 16);
            float ahi = __uint_as_float(aw[c] & 0xffff0000u);
            float blo = __uint_as_float(bw[c] << 16);
            float bhi = __uint_as_float(bw[c] & 0xffff0000u);
            d += alo * blo + ahi * bhi;
        }
    }
    rowval[i] = logf(s) - d * 2.0f;
}

// ---------------- loss = mean(rowval) --------------------------------------
__global__ __launch_bounds__(256) void loss_reduce(
    const float* __restrict__ rowval, float* __restrict__ out)
{
    float s = 0.f;
    for (int i = threadIdx.x; i < N2; i += 256) s += rowval[i];
    s += __shfl_xor(s, 1);
    s += __shfl_xor(s, 2);
    s += __shfl_xor(s, 4);
    s += __shfl_xor(s, 8);
    s += __shfl_xor(s, 16);
    s += __shfl_xor(s, 32);
    __shared__ float wsr[4];
    int lane = threadIdx.x & 63, w = threadIdx.x >> 6;
    if (lane == 0) wsr[w] = s;
    __syncthreads();
    if (threadIdx.x == 0)
        out[0] = (wsr[0] + wsr[1] + wsr[2] + wsr[3]) * (1.0f / N2);
}

extern "C" void kernel_launch(void* const* d_in, const int* in_sizes, int n_in,
                              void* d_out, int out_size, void* d_ws, size_t ws_size,
                              hipStream_t stream)
{
    const float* h1    = (const float*)d_in[0];
    const float* h2    = (const float*)d_in[1];
    const float* W1    = (const float*)d_in[2];
    const float* b1    = (const float*)d_in[3];
    const float* gamma = (const float*)d_in[4];
    const float* beta  = (const float*)d_in[5];
    const float* W2    = (const float*)d_in[6];
    const float* b2    = (const float*)d_in[7];
    float* out = (float*)d_out;

    float* ws      = (float*)d_ws;
    float* Y       = ws;                          // 2*4096*512 = 4,194,304 f
    float* psumc   = Y + (size_t)2 * NB * DHID;   // 16,384 f
    float* psqc    = psumc + 2 * 16 * DHID;       // 16,384 f
    float* bnscale = psqc + 2 * 16 * DHID;        // 1,024 f
    float* bnshift = bnscale + 2 * DHID;          // 1,024 f
    float* psum    = bnshift + 2 * DHID;          // NSPLIT*8192 = 262,144 f
    float* rowval  = psum + (size_t)NSPLIT * N2;  // 8,192 f
    unsigned short* Zb = (unsigned short*)(rowval + N2);  // 8192*128 bf16 = 2MB
    // total ~ 20 MB

    gemm1_kernel    <<<dim3(8, 64, 2), 256, 0, stream>>>(h1, h2, W1, b1, Y);
    bn_stats_partial<<<dim3(8, 16, 2), 256, 0, stream>>>(Y, psumc, psqc);
    bn_stats_final  <<<dim3(4),        256, 0, stream>>>(psumc, psqc, gamma, beta, bnscale, bnshift);
    gemm2_kernel    <<<dim3(64, 2),    256, 0, stream>>>(Y, bnscale, bnshift, W2, b2, Zb, out + 1);
    sim_mfma        <<<dim3(32, NSPLIT), 256, 0, stream>>>(Zb, psum);
    row_finalize    <<<dim3(32),       256, 0, stream>>>(Zb, psum, rowval);
    loss_reduce     <<<dim3(1),        256, 0, stream>>>(rowval, out);
}